// Round 1
// baseline (152.244 us; speedup 1.0000x reference)
//
#include <hip/hip_runtime.h>

// out[b] = M0 @ M1 @ ... @ M95  (4x4 fp32 chain per batch, left-to-right)
//
// Layout: mats[B][96][4][4] row-major fp32.
// Decomposition: 4 lanes per batch; lane (b, r) owns row r of the running
// carry. Each step it loads row r of M_n (16 B); the quad's 4 lanes together
// consume one contiguous 64 B line. The other 3 rows of M_n are obtained via
// DPP quad_perm broadcasts (pure VALU, no LDS, no barriers).

template <int CTRL>
__device__ __forceinline__ float dpp_mov(float x) {
    int xi = __builtin_bit_cast(int, x);
    int r = __builtin_amdgcn_update_dpp(0, xi, CTRL, 0xF, 0xF, true);
    return __builtin_bit_cast(float, r);
}

// Broadcast lane J (within each quad) of all 4 components of m.
template <int J>
__device__ __forceinline__ float4 quad_bcast(float4 m) {
    constexpr int C = J * 0x55;  // quad_perm:[J,J,J,J]
    float4 r;
    r.x = dpp_mov<C>(m.x);
    r.y = dpp_mov<C>(m.y);
    r.z = dpp_mov<C>(m.z);
    r.w = dpp_mov<C>(m.w);
    return r;
}

// v = (row of carry), m = (this lane's row of M). Returns row of carry @ M.
__device__ __forceinline__ float4 row_times_mat(float4 v, float4 m) {
    float4 a = quad_bcast<0>(m);   // M row 0
    float4 acc;
    acc.x = v.x * a.x; acc.y = v.x * a.y; acc.z = v.x * a.z; acc.w = v.x * a.w;
    a = quad_bcast<1>(m);          // M row 1
    acc.x = fmaf(v.y, a.x, acc.x); acc.y = fmaf(v.y, a.y, acc.y);
    acc.z = fmaf(v.y, a.z, acc.z); acc.w = fmaf(v.y, a.w, acc.w);
    a = quad_bcast<2>(m);          // M row 2
    acc.x = fmaf(v.z, a.x, acc.x); acc.y = fmaf(v.z, a.y, acc.y);
    acc.z = fmaf(v.z, a.z, acc.z); acc.w = fmaf(v.z, a.w, acc.w);
    a = quad_bcast<3>(m);          // M row 3
    acc.x = fmaf(v.w, a.x, acc.x); acc.y = fmaf(v.w, a.y, acc.y);
    acc.z = fmaf(v.w, a.z, acc.z); acc.w = fmaf(v.w, a.w, acc.w);
    return acc;
}

__global__ __launch_bounds__(256, 8)
void chainmul_kernel(const float4* __restrict__ mats, float4* __restrict__ out) {
    const int t = blockIdx.x * 256 + threadIdx.x;
    const int b = t >> 2;        // batch
    const int r = t & 3;         // carry row this lane owns
    // 96 matrices * 4 float4 rows = 384 float4 per batch
    const float4* p = mats + (size_t)b * 384 + r;

    float4 v = p[0];             // row r of M0 (initial carry)
    float4 m = p[4];             // row r of M1 (prefetched)

#pragma unroll 4
    for (int n = 1; n < 95; ++n) {
        float4 mn = p[(size_t)4 * (n + 1)];  // prefetch row r of M_{n+1}
        v = row_times_mat(v, m);
        m = mn;
    }
    v = row_times_mat(v, m);     // apply M95

    out[(size_t)b * 4 + r] = v;  // row r of out[b], 64 B per quad, coalesced
}

extern "C" void kernel_launch(void* const* d_in, const int* in_sizes, int n_in,
                              void* d_out, int out_size, void* d_ws, size_t ws_size,
                              hipStream_t stream) {
    const float4* mats = (const float4*)d_in[0];
    float4* out = (float4*)d_out;

    const int B = in_sizes[0] / (96 * 16);   // 131072
    const int threads = B * 4;               // 4 lanes per batch
    const int block = 256;
    const int grid = threads / block;        // 2048 blocks

    hipLaunchKernelGGL(chainmul_kernel, dim3(grid), dim3(block), 0, stream,
                       mats, out);
}

// Round 2
// 147.854 us; speedup vs baseline: 1.0297x; 1.0297x over previous
//
#include <hip/hip_runtime.h>

// out[b] = M0 @ M1 @ ... @ M95  (4x4 fp32 chain per batch, left-to-right)
//
// Layout: mats[B][96][4][4] row-major fp32 = 384 float4 per batch.
//
// Structure: 4 lanes per batch (lane owns one carry row); 16 batches per
// wave. Global->LDS staging via global_load_lds width=16 so each staging
// instruction reads 1024 B CONTIGUOUS (2 batches x 512 B = 8 matrices each),
// fixing the 64 B-granularity scatter of the direct-load version.
// Double-buffered, counted s_waitcnt vmcnt(8), no barriers (waves are
// independent). XOR swizzle (slot ^ (q&7)) applied on the SOURCE global
// address (LDS dest of global_load_lds must stay linear), undone on the
// ds_read side -> 2-way bank pattern (free).

typedef const void __attribute__((address_space(1))) gvoid_t;
typedef void __attribute__((address_space(3))) lvoid_t;

#define GLOAD_LDS16(g, l) \
    __builtin_amdgcn_global_load_lds((gvoid_t*)(g), (lvoid_t*)(l), 16, 0, 0)

template <int CTRL>
__device__ __forceinline__ float dpp_mov(float x) {
    int xi = __builtin_bit_cast(int, x);
    int r = __builtin_amdgcn_update_dpp(0, xi, CTRL, 0xF, 0xF, true);
    return __builtin_bit_cast(float, r);
}

// Broadcast lane J (within each quad) of all 4 components of m.
template <int J>
__device__ __forceinline__ float4 quad_bcast(float4 m) {
    constexpr int C = J * 0x55;  // quad_perm:[J,J,J,J]
    float4 r;
    r.x = dpp_mov<C>(m.x);
    r.y = dpp_mov<C>(m.y);
    r.z = dpp_mov<C>(m.z);
    r.w = dpp_mov<C>(m.w);
    return r;
}

// v = this lane's row of the carry; m = this lane's row of M.
// Returns this lane's row of carry @ M (rows of M broadcast via DPP).
__device__ __forceinline__ float4 row_times_mat(float4 v, float4 m) {
    float4 a = quad_bcast<0>(m);
    float4 acc;
    acc.x = v.x * a.x; acc.y = v.x * a.y; acc.z = v.x * a.z; acc.w = v.x * a.w;
    a = quad_bcast<1>(m);
    acc.x = fmaf(v.y, a.x, acc.x); acc.y = fmaf(v.y, a.y, acc.y);
    acc.z = fmaf(v.y, a.z, acc.z); acc.w = fmaf(v.y, a.w, acc.w);
    a = quad_bcast<2>(m);
    acc.x = fmaf(v.z, a.x, acc.x); acc.y = fmaf(v.z, a.y, acc.y);
    acc.z = fmaf(v.z, a.z, acc.z); acc.w = fmaf(v.z, a.w, acc.w);
    a = quad_bcast<3>(m);
    acc.x = fmaf(v.w, a.x, acc.x); acc.y = fmaf(v.w, a.y, acc.y);
    acc.z = fmaf(v.w, a.z, acc.z); acc.w = fmaf(v.w, a.w, acc.w);
    return acc;
}

__global__ __launch_bounds__(256)
void chainmul_staged(const float4* __restrict__ mats, float4* __restrict__ out) {
    // [wave 4][buf 2][chunk 16][slot 32] float4 = 64 KB
    __shared__ float4 stage[4096];

    const int tid  = threadIdx.x;
    const int wave = tid >> 6;
    const int lane = tid & 63;
    const int q    = lane >> 2;   // batch-in-wave (compute role)
    const int r    = lane & 3;    // carry row this lane owns
    const int wb0  = blockIdx.x * 64 + wave * 16;  // wave's first batch

    // --- staging roles: instr i stages batches (2i, 2i+1) of this wave ---
    const int hl = lane >> 5;     // which of the 2 batches in this instr
    const int s  = lane & 31;     // physical slot within the 512 B chunk

    int src_base[8];              // float4 index into mats, per instr
#pragma unroll
    for (int i = 0; i < 8; ++i) {
        const int bl = 2 * i + hl;                      // batch-in-wave
        // physical slot s holds logical slot (s ^ (bl&7))  [source-side swizzle]
        src_base[i] = (wb0 + bl) * 384 + (s ^ (bl & 7));
    }

    float4* const wlds = &stage[wave * 1024];  // this wave's 16 KB region

    // prologue: stage superstep 0 into buf 0
#pragma unroll
    for (int i = 0; i < 8; ++i)
        GLOAD_LDS16(mats + src_base[i], wlds + i * 64);

    // carry = row r of identity (first multiply is exact: 1*x + 0*y)
    float4 v = make_float4(r == 0 ? 1.0f : 0.0f, r == 1 ? 1.0f : 0.0f,
                           r == 2 ? 1.0f : 0.0f, r == 3 ? 1.0f : 0.0f);

    for (int t = 0; t < 12; ++t) {            // 12 supersteps x 8 matrices
        const int buf = t & 1;
        if (t < 11) {
            float4* const dst = wlds + (buf ^ 1) * 512;
            const int off = (t + 1) * 32;
#pragma unroll
            for (int i = 0; i < 8; ++i)
                GLOAD_LDS16(mats + src_base[i] + off, dst + i * 64);
            // keep the 8 next-superstep loads in flight; wait only for
            // the 8 current-superstep loads (issued one iteration ago)
            asm volatile("s_waitcnt vmcnt(8)" ::: "memory");
        } else {
            asm volatile("s_waitcnt vmcnt(0)" ::: "memory");
        }

        const float4* const chunk = wlds + buf * 512 + q * 32;
#pragma unroll
        for (int m = 0; m < 8; ++m) {
            // undo the source-side swizzle: logical (m*4+r) at phys ^(q&7)
            const float4 row = chunk[(m * 4 + r) ^ (q & 7)];
            v = row_times_mat(v, row);
        }
    }

    out[(size_t)(wb0 + q) * 4 + r] = v;  // 64 B per quad, coalesced
}

extern "C" void kernel_launch(void* const* d_in, const int* in_sizes, int n_in,
                              void* d_out, int out_size, void* d_ws, size_t ws_size,
                              hipStream_t stream) {
    const float4* mats = (const float4*)d_in[0];
    float4* out = (float4*)d_out;

    const int B = in_sizes[0] / (96 * 16);   // 131072
    const int grid = B / 64;                 // 64 batches per 256-thread block
    hipLaunchKernelGGL(chainmul_staged, dim3(grid), dim3(256), 0, stream,
                       mats, out);
}

// Round 3
// 146.597 us; speedup vs baseline: 1.0385x; 1.0086x over previous
//
#include <hip/hip_runtime.h>

// out[b] = M0 @ M1 @ ... @ M95  (4x4 fp32 chain per batch, left-to-right)
// Layout: mats[B][96][4][4] row-major fp32 = 384 float4 per batch.
//
// R3: interior point of (run-length x occupancy):
//   - 4-matrix supersteps (256 B contiguous per batch per superstep)
//   - LDS 32 KB/block -> 5 blocks/CU -> 20 waves/CU (vs R2's 8)
//   - double-buffered, counted s_waitcnt vmcnt(4), no barriers
//     (each wave owns its LDS region; only it reads/writes it)
//   - slot swizzle (s ^ (bl&15)) applied on the per-lane SOURCE address
//     (global_load_lds LDS dest must stay linear); same-set permutation, so
//     each 256 B run is still fully contiguous. Undone on the ds_read side:
//     2 lanes/bank = conflict-free.

typedef const void __attribute__((address_space(1))) gvoid_t;
typedef void __attribute__((address_space(3))) lvoid_t;

#define GLOAD_LDS16(g, l) \
    __builtin_amdgcn_global_load_lds((gvoid_t*)(g), (lvoid_t*)(l), 16, 0, 0)

template <int CTRL>
__device__ __forceinline__ float dpp_mov(float x) {
    int xi = __builtin_bit_cast(int, x);
    int r = __builtin_amdgcn_update_dpp(0, xi, CTRL, 0xF, 0xF, true);
    return __builtin_bit_cast(float, r);
}

// Broadcast lane J (within each quad) of all 4 components of m.
template <int J>
__device__ __forceinline__ float4 quad_bcast(float4 m) {
    constexpr int C = J * 0x55;  // quad_perm:[J,J,J,J]
    float4 r;
    r.x = dpp_mov<C>(m.x);
    r.y = dpp_mov<C>(m.y);
    r.z = dpp_mov<C>(m.z);
    r.w = dpp_mov<C>(m.w);
    return r;
}

// v = this lane's row of the carry; m = this lane's row of M.
// Returns this lane's row of carry @ M (rows of M broadcast via DPP).
__device__ __forceinline__ float4 row_times_mat(float4 v, float4 m) {
    float4 a = quad_bcast<0>(m);
    float4 acc;
    acc.x = v.x * a.x; acc.y = v.x * a.y; acc.z = v.x * a.z; acc.w = v.x * a.w;
    a = quad_bcast<1>(m);
    acc.x = fmaf(v.y, a.x, acc.x); acc.y = fmaf(v.y, a.y, acc.y);
    acc.z = fmaf(v.y, a.z, acc.z); acc.w = fmaf(v.y, a.w, acc.w);
    a = quad_bcast<2>(m);
    acc.x = fmaf(v.z, a.x, acc.x); acc.y = fmaf(v.z, a.y, acc.y);
    acc.z = fmaf(v.z, a.z, acc.z); acc.w = fmaf(v.z, a.w, acc.w);
    a = quad_bcast<3>(m);
    acc.x = fmaf(v.w, a.x, acc.x); acc.y = fmaf(v.w, a.y, acc.y);
    acc.z = fmaf(v.w, a.z, acc.z); acc.w = fmaf(v.w, a.w, acc.w);
    return acc;
}

__global__ __launch_bounds__(256)
void chainmul_staged4(const float4* __restrict__ mats, float4* __restrict__ out) {
    // [wave 4][buf 2][instr 4][lane 64] float4 = 32 KB
    __shared__ float4 stage[2048];

    const int tid  = threadIdx.x;
    const int wave = tid >> 6;
    const int lane = tid & 63;
    const int q    = lane >> 2;   // batch-in-wave (compute role)
    const int r    = lane & 3;    // carry row this lane owns
    const int wb0  = blockIdx.x * 64 + wave * 16;  // wave's first batch

    // --- staging roles: instr i covers batches 4i..4i+3 of this wave ---
    const int blo = lane >> 4;    // batch within the instr's group of 4
    const int sp  = lane & 15;    // physical slot within the 256 B slice

    int src_base[4];              // float4 index into mats, per instr
#pragma unroll
    for (int i = 0; i < 4; ++i) {
        const int bl = 4 * i + blo;
        // phys slot sp holds logical slot (sp ^ (bl&15))  [source-side swizzle]
        src_base[i] = (wb0 + bl) * 384 + (sp ^ (bl & 15));
    }

    float4* const wlds = &stage[wave * 512];  // this wave's 8 KB region

    // prologue: stage superstep 0 (matrices 0..3) into buf 0
#pragma unroll
    for (int i = 0; i < 4; ++i)
        GLOAD_LDS16(mats + src_base[i], wlds + i * 64);

    // carry = row r of identity (first multiply is exact: 1*x + 0*y)
    float4 v = make_float4(r == 0 ? 1.0f : 0.0f, r == 1 ? 1.0f : 0.0f,
                           r == 2 ? 1.0f : 0.0f, r == 3 ? 1.0f : 0.0f);

    for (int t = 0; t < 24; ++t) {            // 24 supersteps x 4 matrices
        const int buf = t & 1;
        if (t < 23) {
            float4* const dst = wlds + (buf ^ 1) * 256;
            const int off = (t + 1) * 16;
#pragma unroll
            for (int i = 0; i < 4; ++i)
                GLOAD_LDS16(mats + src_base[i] + off, dst + i * 64);
            // keep next-superstep loads in flight; wait only for current's
            asm volatile("s_waitcnt vmcnt(4)" ::: "memory");
        } else {
            asm volatile("s_waitcnt vmcnt(0)" ::: "memory");
        }

        const float4* const cbuf = wlds + buf * 256 + q * 16;
#pragma unroll
        for (int m = 0; m < 4; ++m) {
            // undo the source-side swizzle
            const float4 row = cbuf[(m * 4 + r) ^ (q & 15)];
            v = row_times_mat(v, row);
        }
    }

    out[(size_t)(wb0 + q) * 4 + r] = v;  // 64 B per quad, coalesced
}

extern "C" void kernel_launch(void* const* d_in, const int* in_sizes, int n_in,
                              void* d_out, int out_size, void* d_ws, size_t ws_size,
                              hipStream_t stream) {
    const float4* mats = (const float4*)d_in[0];
    float4* out = (float4*)d_out;

    const int B = in_sizes[0] / (96 * 16);   // 131072
    const int grid = B / 64;                 // 64 batches per 256-thread block
    hipLaunchKernelGGL(chainmul_staged4, dim3(grid), dim3(256), 0, stream,
                       mats, out);
}